// Round 7
// baseline (1697.077 us; speedup 1.0000x reference)
//
#include <hip/hip_runtime.h>
#include <math.h>

#define DD 16
#define HH 33
#define HP 36   // padded LDS row stride for w1
#define GG 32
#define G3 (GG*GG*GG)
#define SENT 1e290

typedef unsigned int uint32;

__device__ __forceinline__ float  leakyf(float x){ return x >= 0.f ? x : 0.2f * x; }
__device__ __forceinline__ double leakyd(double x){ return x >= 0.0 ? x : 0.2 * x; }

// monotonic float<->uint encoding for atomic min/max
__device__ __forceinline__ uint32 encf(float f){
    uint32 u = __float_as_uint(f);
    return u ^ ((uint32)((int)u >> 31) | 0x80000000u);
}
__device__ __forceinline__ float decf(uint32 u){
    u ^= (u & 0x80000000u) ? 0x80000000u : 0xFFFFFFFFu;
    return __uint_as_float(u);
}

// top-16 insert (f64). Invariant: all 16 slot values pairwise distinct
// (lane-tagged sentinels + disjoint candidate sets) => exactly one slot == cmax.
__device__ __forceinline__ void insert16d(double (&sd)[16], int (&si)[16], double &cmax,
                                          double s, int ci)
{
    if (s < cmax) {
        #pragma unroll
        for (int j = 0; j < 16; j++) {
            bool r = (sd[j] == cmax);
            sd[j] = r ? s : sd[j];
            si[j] = r ? ci : si[j];
        }
        double a0 = fmax(sd[0], sd[1]),  a1 = fmax(sd[2], sd[3]);
        double a2 = fmax(sd[4], sd[5]),  a3 = fmax(sd[6], sd[7]);
        double a4 = fmax(sd[8], sd[9]),  a5 = fmax(sd[10], sd[11]);
        double a6 = fmax(sd[12], sd[13]), a7 = fmax(sd[14], sd[15]);
        cmax = fmax(fmax(fmax(a0, a1), fmax(a2, a3)), fmax(fmax(a4, a5), fmax(a6, a7)));
    }
}

struct GridP { float x0, y0, z0, ihx, ihy, ihz, hmin; };
__device__ __forceinline__ GridP mkgrid(const uint32* bb){
    GridP g;
    float x0 = decf(bb[0]) - 1e-4f, y0 = decf(bb[1]) - 1e-4f, z0 = decf(bb[2]) - 1e-4f;
    float x1 = decf(bb[3]) + 1e-4f, y1 = decf(bb[4]) + 1e-4f, z1 = decf(bb[5]) + 1e-4f;
    float hx = (x1-x0)/GG, hy = (y1-y0)/GG, hz = (z1-z0)/GG;
    g.x0=x0; g.y0=y0; g.z0=z0;
    g.ihx=1.f/hx; g.ihy=1.f/hy; g.ihz=1.f/hz;
    g.hmin = fminf(hx, fminf(hy, hz));
    return g;
}
__device__ __forceinline__ int cellclamp(float v, float v0, float ih){
    int c = (int)floorf((v - v0) * ih);
    return min(GG-1, max(0, c));
}

// ---------------- bbox over atoms ----------------
__global__ __launch_bounds__(256) void bbox_kernel(
    const float* __restrict__ pts, int n, uint32* __restrict__ bb)
{
    float mn[3] = {1e30f,1e30f,1e30f}, mx[3] = {-1e30f,-1e30f,-1e30f};
    for (int i = blockIdx.x*256 + threadIdx.x; i < n; i += gridDim.x*256) {
        #pragma unroll
        for (int a = 0; a < 3; a++) {
            float v = pts[3*i+a];
            mn[a] = fminf(mn[a], v); mx[a] = fmaxf(mx[a], v);
        }
    }
    #pragma unroll
    for (int s = 1; s < 64; s <<= 1) {
        #pragma unroll
        for (int a = 0; a < 3; a++) {
            mn[a] = fminf(mn[a], __shfl_xor(mn[a], s, 64));
            mx[a] = fmaxf(mx[a], __shfl_xor(mx[a], s, 64));
        }
    }
    if ((threadIdx.x & 63) == 0) {
        #pragma unroll
        for (int a = 0; a < 3; a++) {
            atomicMin(&bb[a],   encf(mn[a]));
            atomicMax(&bb[3+a], encf(mx[a]));
        }
    }
}

// ---------------- histograms (atoms + queries) ----------------
__global__ __launch_bounds__(256) void hist_kernel(
    const float* __restrict__ axyz, int Na, const float* __restrict__ qxyz, int Np,
    const uint32* __restrict__ bb, int* __restrict__ hist_a, int* __restrict__ hist_q)
{
    GridP gp = mkgrid(bb);
    int i = blockIdx.x*256 + threadIdx.x;
    if (i < Na) {
        int cx = cellclamp(axyz[3*i],   gp.x0, gp.ihx);
        int cy = cellclamp(axyz[3*i+1], gp.y0, gp.ihy);
        int cz = cellclamp(axyz[3*i+2], gp.z0, gp.ihz);
        atomicAdd(&hist_a[(cz*GG+cy)*GG+cx], 1);
    } else if (i < Na + Np) {
        int j = i - Na;
        int cx = cellclamp(qxyz[3*j],   gp.x0, gp.ihx);
        int cy = cellclamp(qxyz[3*j+1], gp.y0, gp.ihy);
        int cz = cellclamp(qxyz[3*j+2], gp.z0, gp.ihz);
        atomicAdd(&hist_q[(cz*GG+cy)*GG+cx], 1);
    }
}

// ---------------- exclusive scan (block 0: atoms, block 1: queries) ----------------
__global__ __launch_bounds__(1024) void scan_kernel(
    const int* __restrict__ hist_a, int* __restrict__ offs_a,
    const int* __restrict__ hist_q, int* __restrict__ offs_q, int n)
{
    const int* h = (blockIdx.x == 0) ? hist_a : hist_q;
    int* o = (blockIdx.x == 0) ? offs_a : offs_q;
    __shared__ int part[17];
    int tid = threadIdx.x, lane = tid & 63, wid = tid >> 6;
    int run = 0;
    for (int base = 0; base < n; base += 1024) {
        int i = base + tid;
        int v = (i < n) ? h[i] : 0;
        int x = v;
        #pragma unroll
        for (int s = 1; s < 64; s <<= 1) { int t = __shfl_up(x, s, 64); if (lane >= s) x += t; }
        if (lane == 63) part[wid] = x;
        __syncthreads();
        if (wid == 0) {
            int p = (lane < 16) ? part[lane] : 0;
            #pragma unroll
            for (int s = 1; s < 16; s <<= 1) { int t = __shfl_up(p, s, 64); if (lane >= s) p += t; }
            if (lane < 16) part[lane] = p;
        }
        __syncthreads();
        int woff = wid ? part[wid-1] : 0;
        if (i < n) o[i] = run + woff + x - v;
        int tot = part[15];
        __syncthreads();
        run += tot;
    }
    if (tid == 0) o[n] = run;
}

// ---------------- scatter into cell-sorted order ----------------
__global__ __launch_bounds__(256) void scatter_kernel(
    const float* __restrict__ axyz, int Na, const float* __restrict__ qxyz, int Np,
    const uint32* __restrict__ bb,
    const int* __restrict__ offs_a, int* __restrict__ cur_a,
    const int* __restrict__ offs_q, int* __restrict__ cur_q,
    float4* __restrict__ cand4s, int* __restrict__ aorig,
    float4* __restrict__ sortedq, int* __restrict__ qorig)
{
    GridP gp = mkgrid(bb);
    int i = blockIdx.x*256 + threadIdx.x;
    if (i < Na) {
        float x = axyz[3*i], y = axyz[3*i+1], z = axyz[3*i+2];
        int cx = cellclamp(x, gp.x0, gp.ihx), cy = cellclamp(y, gp.y0, gp.ihy), cz = cellclamp(z, gp.z0, gp.ihz);
        int c = (cz*GG+cy)*GG+cx;
        int pos = offs_a[c] + atomicAdd(&cur_a[c], 1);
        cand4s[pos] = make_float4(x, y, z, 0.f);
        aorig[pos] = i;
    } else if (i < Na + Np) {
        int j = i - Na;
        float x = qxyz[3*j], y = qxyz[3*j+1], z = qxyz[3*j+2];
        int cx = cellclamp(x, gp.x0, gp.ihx), cy = cellclamp(y, gp.y0, gp.ihy), cz = cellclamp(z, gp.z0, gp.ihz);
        int c = (cz*GG+cy)*GG+cx;
        int pos = offs_q[c] + atomicAdd(&cur_q[c], 1);
        sortedq[pos] = make_float4(x, y, z, 0.f);
        qorig[pos] = j;
    }
}

// ---------------- ring search, f64 ranking: 4 lanes per query ----------------
template<bool EXCL>
__device__ __forceinline__ void ring_search(
    const uint32* __restrict__ bb, const float4* __restrict__ cands,
    const int* __restrict__ offs, const int* __restrict__ aorig,
    const float4* __restrict__ qs, const int* __restrict__ qorig, int Nq,
    int* __restrict__ idx_out, double* __restrict__ dst_out, int gblock)
{
    int t = gblock*64 + (threadIdx.x >> 2);
    int sub = threadIdx.x & 3;
    if (t >= Nq) return;
    GridP gp = mkgrid(bb);
    float4 q = qs[t];
    double qx = q.x, qy = q.y, qz = q.z;
    double qn = qx*qx + qy*qy + qz*qz;
    double tqx = 2.0*qx, tqy = 2.0*qy, tqz = 2.0*qz;
    int cxn = (int)floorf((q.x - gp.x0) * gp.ihx);
    int cyn = (int)floorf((q.y - gp.y0) * gp.ihy);
    int czn = (int)floorf((q.z - gp.z0) * gp.ihz);
    // lane-tagged sentinels: all 64 sentinel values across the 4-lane group are
    // distinct, so the merge below never creates duplicate slot values (the
    // round-6 nondeterminism bug: identical sentinels collided after merge,
    // breaking the one-slot==cmax invariant -> duplicated/dropped neighbors).
    double sd[16]; int si[16];
    #pragma unroll
    for (int j = 0; j < 16; j++) { sd[j] = SENT * (double)(sub*16 + j + 1); si[j] = 0; }
    double cmax = SENT * (double)(sub*16 + 16);
    double h2 = (double)gp.hmin * (double)gp.hmin;

    for (int r = 0; r <= 3*GG; ++r) {
        if (r >= 1) {
            // gm = min over 4 lanes of per-lane 16th-best: upper bound on the
            // group's final d16^2 - qn. Sentinel-valued gm (~1e290) never breaks.
            double gm = fmin(cmax, __shfl_xor(cmax, 1, 64));
            gm = fmin(gm, __shfl_xor(gm, 2, 64));
            double rb = (double)(r - 1);
            if (rb*rb*h2 > gm + qn + 1e-6) break;   // d^2 = qn + s; conservative
        }
        for (int dz = -r; dz <= r; ++dz) {
            int cz = czn + dz; if (cz < 0 || cz >= GG) continue;
            bool zf = (dz == -r) || (dz == r);
            for (int dy = -r; dy <= r; ++dy) {
                int cy = cyn + dy; if (cy < 0 || cy >= GG) continue;
                bool yf = zf || (dy == -r) || (dy == r);
                for (int dx = -r; dx <= r; ++dx) {
                    if (!yf && dx != -r && dx != r) continue;  // shell only
                    int cx = cxn + dx; if (cx < 0 || cx >= GG) continue;
                    int c = (cz*GG + cy)*GG + cx;
                    int cs = offs[c], ce = offs[c+1];
                    for (int p = cs + sub; p < ce; p += 4) {
                        if (EXCL && p == t) continue;   // self (queries == sorted atoms)
                        float4 cv = cands[p];
                        double gx = cv.x, gy = cv.y, gz = cv.z;
                        // s = |y|^2 - 2 q.y in f64 (exact ranking; no ties)
                        double s = gx*(gx - tqx) + gy*(gy - tqy) + gz*(gz - tqz);
                        insert16d(sd, si, cmax, s, p);
                    }
                }
            }
        }
    }

    // butterfly merge across the 4 lanes (snapshot exchange, then insert);
    // exchanged sets are disjoint from receiver's at every stage.
    #pragma unroll
    for (int m = 1; m <= 2; m <<= 1) {
        double td[16]; int ti[16];
        #pragma unroll
        for (int j = 0; j < 16; j++) {
            td[j] = __shfl_xor(sd[j], m, 64);
            ti[j] = __shfl_xor(si[j], m, 64);
        }
        #pragma unroll
        for (int j = 0; j < 16; j++) insert16d(sd, si, cmax, td[j], ti[j]);
    }

    if (sub == 0) {
        // bitonic sort 16 ascending by s: matches np's sorted top_k order
        #pragma unroll
        for (int kk = 2; kk <= 16; kk <<= 1) {
            #pragma unroll
            for (int jj = kk >> 1; jj > 0; jj >>= 1) {
                #pragma unroll
                for (int i = 0; i < 16; i++) {
                    int l = i ^ jj;
                    if (l > i) {
                        bool up = ((i & kk) == 0);
                        bool sw = up ? (sd[i] > sd[l]) : (sd[i] < sd[l]);
                        double fa = sw ? sd[l] : sd[i], fb = sw ? sd[i] : sd[l];
                        int    ia = sw ? si[l] : si[i], ib = sw ? si[i] : si[l];
                        sd[i] = fa; sd[l] = fb; si[i] = ia; si[l] = ib;
                    }
                }
            }
        }
        size_t ob = (size_t)qorig[t] * 16;
        #pragma unroll
        for (int j = 0; j < 16; j++) {
            int p = si[j];
            float4 cv = cands[p];
            double dxx = qx - (double)cv.x, dyy = qy - (double)cv.y, dzz = qz - (double)cv.z;
            idx_out[ob + j] = aorig[p];
            dst_out[ob + j] = dxx*dxx + dyy*dyy + dzz*dzz;   // f64 exact recompute
        }
    }
}

__global__ __launch_bounds__(256) void ring_both(
    const uint32* __restrict__ bb, const float4* __restrict__ cands,
    const int* __restrict__ offs_a, const int* __restrict__ aorig, int Na,
    const float4* __restrict__ sortedq, const int* __restrict__ qorig, int Np,
    int* __restrict__ idx1, double* __restrict__ dst1,
    int* __restrict__ idx2, double* __restrict__ dst2, int nblk1)
{
    if ((int)blockIdx.x < nblk1)
        ring_search<true >(bb, cands, offs_a, aorig, cands,   aorig, Na, idx1, dst1, blockIdx.x);
    else
        ring_search<false>(bb, cands, offs_a, aorig, sortedq, qorig, Np, idx2, dst2, blockIdx.x - nblk1);
}

// ---------------- fallback brute-force KNN (f64 ranking; ws too small) ----------------
template<bool EXCL>
__device__ __forceinline__ void knn_blockd(
    float4* s_cand, const float* __restrict__ q_xyz, int Nq,
    const float* __restrict__ db, int Nd,
    int* __restrict__ idx_out, double* __restrict__ dist_out, int qblock)
{
    int tid = threadIdx.x;
    int qi = qblock*256 + tid;
    bool active = qi < Nq;
    int q = active ? qi : 0;
    double qx = q_xyz[q*3], qy = q_xyz[q*3+1], qz = q_xyz[q*3+2];
    double tqx = 2.0*qx, tqy = 2.0*qy, tqz = 2.0*qz;
    double sd[16]; int si[16];
    #pragma unroll
    for (int j = 0; j < 16; j++) { sd[j] = SENT*(double)(j+1); si[j] = 0; }
    double cmax = SENT*16.0;
    for (int t0 = 0; t0 < Nd; t0 += 256) {
        __syncthreads();
        int c = t0 + tid;
        if (c < Nd) s_cand[tid] = make_float4(db[c*3], db[c*3+1], db[c*3+2], 0.f);
        __syncthreads();
        int lim = min(256, Nd - t0);
        for (int u = 0; u < lim; u++) {
            float4 cv = s_cand[u];
            double gx = cv.x, gy = cv.y, gz = cv.z;
            double s = gx*(gx - tqx) + gy*(gy - tqy) + gz*(gz - tqz);
            if (EXCL && (t0 + u == q)) continue;
            insert16d(sd, si, cmax, s, t0 + u);
        }
    }
    if (active) {
        #pragma unroll
        for (int kk = 2; kk <= 16; kk <<= 1)
            #pragma unroll
            for (int jj = kk >> 1; jj > 0; jj >>= 1)
                #pragma unroll
                for (int i = 0; i < 16; i++) {
                    int l = i ^ jj;
                    if (l > i) {
                        bool up = ((i & kk) == 0);
                        bool sw = up ? (sd[i] > sd[l]) : (sd[i] < sd[l]);
                        double fa = sw ? sd[l] : sd[i], fb = sw ? sd[i] : sd[l];
                        int    ia = sw ? si[l] : si[i], ib = sw ? si[i] : si[l];
                        sd[i] = fa; sd[l] = fb; si[i] = ia; si[l] = ib;
                    }
                }
        #pragma unroll
        for (int j = 0; j < 16; j++) {
            int ci = si[j];
            double dxx = qx - (double)db[ci*3], dyy = qy - (double)db[ci*3+1], dzz = qz - (double)db[ci*3+2];
            idx_out[(size_t)qi*16 + j] = ci;
            dist_out[(size_t)qi*16 + j] = dxx*dxx + dyy*dyy + dzz*dzz;
        }
    }
}

__global__ __launch_bounds__(256) void knn_both(
    const float* __restrict__ xyz, const float* __restrict__ atom_xyz,
    int Np, int Na,
    int* __restrict__ idx1, double* __restrict__ dst1,
    int* __restrict__ idx2, double* __restrict__ dst2, int nblk1)
{
    __shared__ float4 s_cand[256];
    if ((int)blockIdx.x < nblk1)
        knn_blockd<true >(s_cand, atom_xyz, Na, atom_xyz, Na, idx1, dst1, blockIdx.x);
    else
        knn_blockd<false>(s_cand, xyz, Np, atom_xyz, Na, idx2, dst2, blockIdx.x - nblk1);
}

// ---------------- atomtypes MLP (f32) ----------------
__global__ __launch_bounds__(256) void tt_kernel(
    const float* __restrict__ at,
    const float* __restrict__ w1, const float* __restrict__ b1,
    const float* __restrict__ w2, const float* __restrict__ b2,
    float* __restrict__ out, int Na)
{
    __shared__ float s_w1[DD*DD], s_w2[DD*DD], s_b1[DD], s_b2[DD];
    int tid = threadIdx.x;
    s_w1[tid & 255] = w1[tid & 255];
    s_w2[tid & 255] = w2[tid & 255];
    if (tid < DD) { s_b1[tid] = b1[tid]; s_b2[tid] = b2[tid]; }
    __syncthreads();
    int n = blockIdx.x*256 + tid;
    if (n >= Na) return;
    float f[DD];
    const float4* fp = reinterpret_cast<const float4*>(at + (size_t)n*DD);
    #pragma unroll
    for (int i = 0; i < 4; i++) { float4 v = fp[i]; f[4*i]=v.x; f[4*i+1]=v.y; f[4*i+2]=v.z; f[4*i+3]=v.w; }
    float h[DD];
    #pragma unroll
    for (int j = 0; j < DD; j++) h[j] = s_b1[j];
    #pragma unroll
    for (int e = 0; e < DD; e++) {
        float fe = f[e];
        #pragma unroll
        for (int j = 0; j < DD; j++) h[j] = fmaf(fe, s_w1[e*DD+j], h[j]);
    }
    #pragma unroll
    for (int j = 0; j < DD; j++) h[j] = leakyf(h[j]);
    float m[DD];
    #pragma unroll
    for (int j = 0; j < DD; j++) m[j] = s_b2[j];
    #pragma unroll
    for (int e = 0; e < DD; e++) {
        float he = h[e];
        #pragma unroll
        for (int j = 0; j < DD; j++) m[j] = fmaf(he, s_w2[e*DD+j], m[j]);
    }
    float4* op = reinterpret_cast<float4*>(out + (size_t)n*DD);
    #pragma unroll
    for (int i = 0; i < 4; i++) op[i] = make_float4(m[4*i], m[4*i+1], m[4*i+2], m[4*i+3]);
}

// ---------------- message-passing layer (f32 MLP/state, f64 k-sum + GN) ----------------
__global__ __launch_bounds__(256) void mp_kernel(
    const float* __restrict__ self_feat,   // null => ones (em layer 0)
    const float* __restrict__ nbr_feat,
    const int*    __restrict__ idx,
    const double* __restrict__ dists,
    const float* __restrict__ w1, const float* __restrict__ b1,
    const float* __restrict__ w2, const float* __restrict__ b2,
    const float* __restrict__ gamma, const float* __restrict__ beta,
    float* __restrict__ out_feat, int N)
{
    __shared__ float s_w1[HH*HP];
    __shared__ float s_w2[HH*DD];
    __shared__ float s_b1[HH];
    __shared__ float s_b2[DD], s_g[DD], s_bt[DD];
    int tid = threadIdx.x;
    for (int i = tid; i < HH*HH; i += 256) s_w1[(i/HH)*HP + (i%HH)] = w1[i];
    for (int i = tid; i < HH*DD; i += 256) s_w2[i] = w2[i];
    if (tid < HH) s_b1[tid] = b1[tid];
    if (tid < DD) { s_b2[tid] = b2[tid]; s_g[tid] = gamma[tid]; s_bt[tid] = beta[tid]; }
    __syncthreads();

    int n = blockIdx.x*16 + (tid >> 4);
    int k = tid & 15;
    bool active = n < N;
    int nn = active ? n : (N-1);

    float f[HH];
    if (self_feat) {
        const float4* sp = reinterpret_cast<const float4*>(self_feat + (size_t)nn*DD);
        #pragma unroll
        for (int i = 0; i < 4; i++) { float4 v = sp[i]; f[4*i]=v.x; f[4*i+1]=v.y; f[4*i+2]=v.z; f[4*i+3]=v.w; }
    } else {
        #pragma unroll
        for (int i = 0; i < DD; i++) f[i] = 1.f;
    }
    int nb = idx[(size_t)nn*16 + k];
    {
        const float4* npp = reinterpret_cast<const float4*>(nbr_feat + (size_t)nb*DD);
        #pragma unroll
        for (int i = 0; i < 4; i++) { float4 v = npp[i]; f[DD+4*i]=v.x; f[DD+4*i+1]=v.y; f[DD+4*i+2]=v.z; f[DD+4*i+3]=v.w; }
    }
    f[2*DD] = (float)dists[(size_t)nn*16 + k];

    float h[HH];
    #pragma unroll
    for (int j = 0; j < HH; j++) h[j] = s_b1[j];
    #pragma unroll
    for (int e = 0; e < HH; e++) {
        float fe = f[e];
        const float* wr = &s_w1[e*HP];
        #pragma unroll
        for (int j = 0; j < HH; j++) h[j] = fmaf(fe, wr[j], h[j]);
    }
    #pragma unroll
    for (int j = 0; j < HH; j++) h[j] = leakyf(h[j]);

    float m[DD];
    #pragma unroll
    for (int j = 0; j < DD; j++) m[j] = s_b2[j];
    #pragma unroll
    for (int e = 0; e < HH; e++) {
        float he = h[e];
        const float* wr = &s_w2[e*DD];
        #pragma unroll
        for (int j = 0; j < DD; j++) m[j] = fmaf(he, wr[j], m[j]);
    }

    // k-sum in f64: 16-lane-group butterfly
    double md[DD];
    #pragma unroll
    for (int j = 0; j < DD; j++) md[j] = (double)m[j];
    #pragma unroll
    for (int s = 1; s < 16; s <<= 1) {
        #pragma unroll
        for (int j = 0; j < DD; j++) md[j] += __shfl_xor(md[j], s, 64);
    }

    // group norm over D=16 in f64
    double mu = 0.0;
    #pragma unroll
    for (int j = 0; j < DD; j++) mu += md[j];
    mu *= (1.0/DD);
    double var = 0.0;
    #pragma unroll
    for (int j = 0; j < DD; j++) { double d = md[j] - mu; var = fma(d, d, var); }
    var *= (1.0/DD);
    double inv = 1.0 / sqrt(var + 1e-5);
    double mk = 0.0;   // static-index select (no runtime reg indexing)
    #pragma unroll
    for (int j = 0; j < DD; j++) mk = (j == k) ? md[j] : mk;
    double g = (mk - mu)*inv*(double)s_g[k] + (double)s_bt[k];
    double act = leakyd(g);
    double base = self_feat ? (double)self_feat[(size_t)nn*DD + k] : 1.0;
    if (active) out_feat[(size_t)n*DD + k] = (float)(base + act);
}

extern "C" void kernel_launch(void* const* d_in, const int* in_sizes, int n_in,
                              void* d_out, int out_size, void* d_ws, size_t ws_size,
                              hipStream_t stream)
{
    const float* xyz       = (const float*)d_in[0];
    const float* atom_xyz  = (const float*)d_in[1];
    const float* atomtypes = (const float*)d_in[2];
    const float* tt_w1 = (const float*)d_in[5];
    const float* tt_b1 = (const float*)d_in[6];
    const float* tt_w2 = (const float*)d_in[7];
    const float* tt_b2 = (const float*)d_in[8];
    const float* aa_w1 = (const float*)d_in[9];
    const float* aa_b1 = (const float*)d_in[10];
    const float* aa_w2 = (const float*)d_in[11];
    const float* aa_b2 = (const float*)d_in[12];
    const float* aa_g  = (const float*)d_in[13];
    const float* aa_bt = (const float*)d_in[14];
    const float* em_w1 = (const float*)d_in[15];
    const float* em_b1 = (const float*)d_in[16];
    const float* em_w2 = (const float*)d_in[17];
    const float* em_b2 = (const float*)d_in[18];
    const float* em_g  = (const float*)d_in[19];
    const float* em_bt = (const float*)d_in[20];

    int Np = in_sizes[0] / 3;
    int Na = in_sizes[1] / 3;

    char* w = (char*)d_ws;
    size_t off = 0;
    auto alloc = [&](size_t bytes) -> void* {
        void* p = w + off; off += (bytes + 15) & ~(size_t)15; return p;
    };
    uint32*  bb      = (uint32*)alloc(24);
    int*     hist_a  = (int*)alloc((size_t)G3*4);
    int*     cur_a   = (int*)alloc((size_t)G3*4);
    int*     hist_q  = (int*)alloc((size_t)G3*4);
    int*     cur_q   = (int*)alloc((size_t)G3*4);
    int*     offs_a  = (int*)alloc((size_t)(G3+1)*4);
    int*     offs_q  = (int*)alloc((size_t)(G3+1)*4);
    float4*  cand4s  = (float4*)alloc((size_t)Na*16);
    int*     aorig   = (int*)alloc((size_t)Na*4);
    float4*  sortedq = (float4*)alloc((size_t)Np*16);
    int*     qorig   = (int*)alloc((size_t)Np*4);
    float*   bufA    = (float*)alloc((size_t)Na*DD*4);
    float*   bufB    = (float*)alloc((size_t)Na*DD*4);
    int*     idx1    = (int*)alloc((size_t)Na*16*4);
    double*  dst1    = (double*)alloc((size_t)Na*16*8);
    int*     idx2    = (int*)alloc((size_t)Np*16*4);
    double*  dst2    = (double*)alloc((size_t)Np*16*8);
    size_t need = off;
    float* pe = (float*)d_out;

    if (ws_size >= need) {
        hipMemsetAsync(bb, 0xFF, 12, stream);                    // min slots
        hipMemsetAsync((char*)bb + 12, 0, 12, stream);           // max slots
        hipMemsetAsync(hist_a, 0, (size_t)4*G3*4, stream);       // hist_a,cur_a,hist_q,cur_q
        bbox_kernel<<<dim3(40), 256, 0, stream>>>(atom_xyz, Na, bb);
        int gb = (Na + Np + 255) / 256;
        hist_kernel<<<dim3(gb), 256, 0, stream>>>(atom_xyz, Na, xyz, Np, bb, hist_a, hist_q);
        scan_kernel<<<dim3(2), 1024, 0, stream>>>(hist_a, offs_a, hist_q, offs_q, G3);
        scatter_kernel<<<dim3(gb), 256, 0, stream>>>(atom_xyz, Na, xyz, Np, bb,
            offs_a, cur_a, offs_q, cur_q, cand4s, aorig, sortedq, qorig);
        int nblk1 = (Na + 63) / 64, nblk2 = (Np + 63) / 64;
        ring_both<<<dim3(nblk1 + nblk2), 256, 0, stream>>>(
            bb, cand4s, offs_a, aorig, Na, sortedq, qorig, Np,
            idx1, dst1, idx2, dst2, nblk1);
    } else {
        // fallback: brute-force f64 path with compact layout
        char* v = (char*)d_ws; size_t o2 = 0;
        auto alloc2 = [&](size_t bytes) -> void* {
            void* p = v + o2; o2 += (bytes + 15) & ~(size_t)15; return p;
        };
        bufA = (float*)alloc2((size_t)Na*DD*4);
        bufB = (float*)alloc2((size_t)Na*DD*4);
        idx1 = (int*)alloc2((size_t)Na*16*4);
        dst1 = (double*)alloc2((size_t)Na*16*8);
        idx2 = (int*)alloc2((size_t)Np*16*4);
        dst2 = (double*)alloc2((size_t)Np*16*8);
        int qb1 = (Na + 255)/256, qb2 = (Np + 255)/256;
        knn_both<<<dim3(qb1 + qb2), 256, 0, stream>>>(
            xyz, atom_xyz, Np, Na, idx1, dst1, idx2, dst2, qb1);
    }

    tt_kernel<<<dim3((Na + 255)/256), 256, 0, stream>>>(
        atomtypes, tt_w1, tt_b1, tt_w2, tt_b2, bufA, Na);

    int ga = (Na + 15)/16, ge = (Np + 15)/16;
    // aa layers: ping-pong A->B->A->B
    mp_kernel<<<ga, 256, 0, stream>>>(bufA, bufA, idx1, dst1,
        aa_w1, aa_b1, aa_w2, aa_b2, aa_g, aa_bt, bufB, Na);
    mp_kernel<<<ga, 256, 0, stream>>>(bufB, bufB, idx1, dst1,
        aa_w1 + HH*HH, aa_b1 + HH, aa_w2 + HH*DD, aa_b2 + DD, aa_g + DD, aa_bt + DD, bufA, Na);
    mp_kernel<<<ga, 256, 0, stream>>>(bufA, bufA, idx1, dst1,
        aa_w1 + 2*HH*HH, aa_b1 + 2*HH, aa_w2 + 2*HH*DD, aa_b2 + 2*DD, aa_g + 2*DD, aa_bt + 2*DD, bufB, Na);
    // em layers: atom features fixed (bufB); pe self-only reads -> in-place in d_out
    mp_kernel<<<ge, 256, 0, stream>>>(nullptr, bufB, idx2, dst2,
        em_w1, em_b1, em_w2, em_b2, em_g, em_bt, pe, Np);
    mp_kernel<<<ge, 256, 0, stream>>>(pe, bufB, idx2, dst2,
        em_w1 + HH*HH, em_b1 + HH, em_w2 + HH*DD, em_b2 + DD, em_g + DD, em_bt + DD, pe, Np);
    mp_kernel<<<ge, 256, 0, stream>>>(pe, bufB, idx2, dst2,
        em_w1 + 2*HH*HH, em_b1 + 2*HH, em_w2 + 2*HH*DD, em_b2 + 2*DD, em_g + 2*DD, em_bt + 2*DD, pe, Np);
}

// Round 9
// 1228.387 us; speedup vs baseline: 1.3815x; 1.3815x over previous
//
#include <hip/hip_runtime.h>
#include <math.h>

#define DD 16
#define HH 33
#define HP 36   // padded LDS row stride for w1
#define GG 32
#define G3 (GG*GG*GG)
#define SENT 1e290

typedef unsigned int uint32;

__device__ __forceinline__ float  leakyf(float x){ return x >= 0.f ? x : 0.2f * x; }
__device__ __forceinline__ double leakyd(double x){ return x >= 0.0 ? x : 0.2 * x; }

// monotonic float<->uint encoding for atomic min/max
__device__ __forceinline__ uint32 encf(float f){
    uint32 u = __float_as_uint(f);
    return u ^ ((uint32)((int)u >> 31) | 0x80000000u);
}
__device__ __forceinline__ float decf(uint32 u){
    u ^= (u & 0x80000000u) ? 0x80000000u : 0xFFFFFFFFu;
    return __uint_as_float(u);
}

// top-16 insert (f64). Invariant: slot values pairwise distinct (distinct
// sentinels + exact-f64 scores of distinct atoms) => exactly one slot == cmax.
__device__ __forceinline__ void insert16d(double (&sd)[16], int (&si)[16], double &cmax,
                                          double s, int ci)
{
    if (s < cmax) {
        #pragma unroll
        for (int j = 0; j < 16; j++) {
            bool r = (sd[j] == cmax);
            sd[j] = r ? s : sd[j];
            si[j] = r ? ci : si[j];
        }
        double a0 = fmax(sd[0], sd[1]),  a1 = fmax(sd[2], sd[3]);
        double a2 = fmax(sd[4], sd[5]),  a3 = fmax(sd[6], sd[7]);
        double a4 = fmax(sd[8], sd[9]),  a5 = fmax(sd[10], sd[11]);
        double a6 = fmax(sd[12], sd[13]), a7 = fmax(sd[14], sd[15]);
        cmax = fmax(fmax(fmax(a0, a1), fmax(a2, a3)), fmax(fmax(a4, a5), fmax(a6, a7)));
    }
}

struct GridP { float x0, y0, z0, ihx, ihy, ihz, hmin; };
__device__ __forceinline__ GridP mkgrid(const uint32* bb){
    GridP g;
    float x0 = decf(bb[0]) - 1e-4f, y0 = decf(bb[1]) - 1e-4f, z0 = decf(bb[2]) - 1e-4f;
    float x1 = decf(bb[3]) + 1e-4f, y1 = decf(bb[4]) + 1e-4f, z1 = decf(bb[5]) + 1e-4f;
    float hx = (x1-x0)/GG, hy = (y1-y0)/GG, hz = (z1-z0)/GG;
    g.x0=x0; g.y0=y0; g.z0=z0;
    g.ihx=1.f/hx; g.ihy=1.f/hy; g.ihz=1.f/hz;
    g.hmin = fminf(hx, fminf(hy, hz));
    return g;
}
__device__ __forceinline__ int cellclamp(float v, float v0, float ih){
    int c = (int)floorf((v - v0) * ih);
    return min(GG-1, max(0, c));
}

// ---------------- bbox over atoms ----------------
__global__ __launch_bounds__(256) void bbox_kernel(
    const float* __restrict__ pts, int n, uint32* __restrict__ bb)
{
    float mn[3] = {1e30f,1e30f,1e30f}, mx[3] = {-1e30f,-1e30f,-1e30f};
    for (int i = blockIdx.x*256 + threadIdx.x; i < n; i += gridDim.x*256) {
        #pragma unroll
        for (int a = 0; a < 3; a++) {
            float v = pts[3*i+a];
            mn[a] = fminf(mn[a], v); mx[a] = fmaxf(mx[a], v);
        }
    }
    #pragma unroll
    for (int s = 1; s < 64; s <<= 1) {
        #pragma unroll
        for (int a = 0; a < 3; a++) {
            mn[a] = fminf(mn[a], __shfl_xor(mn[a], s, 64));
            mx[a] = fmaxf(mx[a], __shfl_xor(mx[a], s, 64));
        }
    }
    if ((threadIdx.x & 63) == 0) {
        #pragma unroll
        for (int a = 0; a < 3; a++) {
            atomicMin(&bb[a],   encf(mn[a]));
            atomicMax(&bb[3+a], encf(mx[a]));
        }
    }
}

// ---------------- histograms (atoms + queries) ----------------
__global__ __launch_bounds__(256) void hist_kernel(
    const float* __restrict__ axyz, int Na, const float* __restrict__ qxyz, int Np,
    const uint32* __restrict__ bb, int* __restrict__ hist_a, int* __restrict__ hist_q)
{
    GridP gp = mkgrid(bb);
    int i = blockIdx.x*256 + threadIdx.x;
    if (i < Na) {
        int cx = cellclamp(axyz[3*i],   gp.x0, gp.ihx);
        int cy = cellclamp(axyz[3*i+1], gp.y0, gp.ihy);
        int cz = cellclamp(axyz[3*i+2], gp.z0, gp.ihz);
        atomicAdd(&hist_a[(cz*GG+cy)*GG+cx], 1);
    } else if (i < Na + Np) {
        int j = i - Na;
        int cx = cellclamp(qxyz[3*j],   gp.x0, gp.ihx);
        int cy = cellclamp(qxyz[3*j+1], gp.y0, gp.ihy);
        int cz = cellclamp(qxyz[3*j+2], gp.z0, gp.ihz);
        atomicAdd(&hist_q[(cz*GG+cy)*GG+cx], 1);
    }
}

// ---------------- exclusive scan (block 0: atoms, block 1: queries) ----------------
__global__ __launch_bounds__(1024) void scan_kernel(
    const int* __restrict__ hist_a, int* __restrict__ offs_a,
    const int* __restrict__ hist_q, int* __restrict__ offs_q, int n)
{
    const int* h = (blockIdx.x == 0) ? hist_a : hist_q;
    int* o = (blockIdx.x == 0) ? offs_a : offs_q;
    __shared__ int part[17];
    int tid = threadIdx.x, lane = tid & 63, wid = tid >> 6;
    int run = 0;
    for (int base = 0; base < n; base += 1024) {
        int i = base + tid;
        int v = (i < n) ? h[i] : 0;
        int x = v;
        #pragma unroll
        for (int s = 1; s < 64; s <<= 1) { int t = __shfl_up(x, s, 64); if (lane >= s) x += t; }
        if (lane == 63) part[wid] = x;
        __syncthreads();
        if (wid == 0) {
            int p = (lane < 16) ? part[lane] : 0;
            #pragma unroll
            for (int s = 1; s < 16; s <<= 1) { int t = __shfl_up(p, s, 64); if (lane >= s) p += t; }
            if (lane < 16) part[lane] = p;
        }
        __syncthreads();
        int woff = wid ? part[wid-1] : 0;
        if (i < n) o[i] = run + woff + x - v;
        int tot = part[15];
        __syncthreads();
        run += tot;
    }
    if (tid == 0) o[n] = run;
}

// ---------------- scatter into cell-sorted order ----------------
__global__ __launch_bounds__(256) void scatter_kernel(
    const float* __restrict__ axyz, int Na, const float* __restrict__ qxyz, int Np,
    const uint32* __restrict__ bb,
    const int* __restrict__ offs_a, int* __restrict__ cur_a,
    const int* __restrict__ offs_q, int* __restrict__ cur_q,
    float4* __restrict__ cand4s, int* __restrict__ aorig,
    float4* __restrict__ sortedq, int* __restrict__ qorig)
{
    GridP gp = mkgrid(bb);
    int i = blockIdx.x*256 + threadIdx.x;
    if (i < Na) {
        float x = axyz[3*i], y = axyz[3*i+1], z = axyz[3*i+2];
        int cx = cellclamp(x, gp.x0, gp.ihx), cy = cellclamp(y, gp.y0, gp.ihy), cz = cellclamp(z, gp.z0, gp.ihz);
        int c = (cz*GG+cy)*GG+cx;
        int pos = offs_a[c] + atomicAdd(&cur_a[c], 1);
        cand4s[pos] = make_float4(x, y, z, 0.f);
        aorig[pos] = i;
    } else if (i < Na + Np) {
        int j = i - Na;
        float x = qxyz[3*j], y = qxyz[3*j+1], z = qxyz[3*j+2];
        int cx = cellclamp(x, gp.x0, gp.ihx), cy = cellclamp(y, gp.y0, gp.ihy), cz = cellclamp(z, gp.z0, gp.ihz);
        int c = (cz*GG+cy)*GG+cx;
        int pos = offs_q[c] + atomicAdd(&cur_q[c], 1);
        sortedq[pos] = make_float4(x, y, z, 0.f);
        qorig[pos] = j;
    }
}

// ---------------- ring search: ONE lane per query, contiguous row-runs ----------------
// Cells consecutive in x are contiguous in cand4s (c=(cz*GG+cy)*GG+cx), so a row
// [cx_lo..cx_hi] costs 2 offset loads + one contiguous scan. Lane breaks on its
// OWN true 16th-best (no 4-lane criterion inflation — the round-7 cost bug).
template<bool EXCL>
__device__ __forceinline__ void ring_search(
    const uint32* __restrict__ bb, const float4* __restrict__ cands,
    const int* __restrict__ offs, const int* __restrict__ aorig,
    const float4* __restrict__ qs, const int* __restrict__ qorig, int Nq,
    int* __restrict__ idx_out, double* __restrict__ dst_out, int t)
{
    if (t >= Nq) return;
    GridP gp = mkgrid(bb);
    float4 q = qs[t];
    double qx = q.x, qy = q.y, qz = q.z;
    double qn = qx*qx + qy*qy + qz*qz;
    double tqx = 2.0*qx, tqy = 2.0*qy, tqz = 2.0*qz;
    int cxn = (int)floorf((q.x - gp.x0) * gp.ihx);
    int cyn = (int)floorf((q.y - gp.y0) * gp.ihy);
    int czn = (int)floorf((q.z - gp.z0) * gp.ihz);
    double sd[16]; int si[16];
    #pragma unroll
    for (int j = 0; j < 16; j++) { sd[j] = SENT * (double)(j + 1); si[j] = 0; }
    double cmax = SENT * 16.0;

    auto scan_run = [&](int cz, int cy, int cl, int ch) {
        if ((unsigned)cz >= GG || (unsigned)cy >= GG) return;
        cl = max(cl, 0); ch = min(ch, GG - 1);
        if (cl > ch) return;
        int base = (cz*GG + cy)*GG;
        int p0 = offs[base + cl], p1 = offs[base + ch + 1];
        for (int p = p0; p < p1; ++p) {
            if (EXCL && p == t) continue;   // self (queries == sorted atoms)
            float4 cv = cands[p];
            double gx = cv.x, gy = cv.y, gz = cv.z;
            double s = gx*(gx - tqx) + gy*(gy - tqy) + gz*(gz - tqz);  // exact f64
            insert16d(sd, si, cmax, s, p);
        }
    };

    // r = 0: own cell
    scan_run(czn, cyn, cxn, cxn);
    // expanding shells; after box r fully scanned, unscanned atoms are >= r*hmin away
    for (int r = 1; r <= 3*GG; ++r) {
        if (cmax < SENT) {
            double rb = (double)(r - 1) * (double)gp.hmin;
            if (rb*rb > qn + cmax + 1e-6) break;   // d16^2 = qn + cmax
        }
        for (int dz = -r; dz <= r; ++dz) {
            int cz = czn + dz;
            bool zface = (dz == -r) || (dz == r);
            for (int dy = -r; dy <= r; ++dy) {
                int cy = cyn + dy;
                if (zface || dy == -r || dy == r) {
                    scan_run(cz, cy, cxn - r, cxn + r);          // full row
                } else {
                    scan_run(cz, cy, cxn - r, cxn - r);          // two end cells
                    scan_run(cz, cy, cxn + r, cxn + r);
                }
            }
        }
    }

    // bitonic sort 16 ascending by s: matches np's sorted top_k order
    #pragma unroll
    for (int kk = 2; kk <= 16; kk <<= 1) {
        #pragma unroll
        for (int jj = kk >> 1; jj > 0; jj >>= 1) {
            #pragma unroll
            for (int i = 0; i < 16; i++) {
                int l = i ^ jj;
                if (l > i) {
                    bool up = ((i & kk) == 0);
                    bool sw = up ? (sd[i] > sd[l]) : (sd[i] < sd[l]);
                    double fa = sw ? sd[l] : sd[i], fb = sw ? sd[i] : sd[l];
                    int    ia = sw ? si[l] : si[i], ib = sw ? si[i] : si[l];
                    sd[i] = fa; sd[l] = fb; si[i] = ia; si[l] = ib;
                }
            }
        }
    }
    size_t ob = (size_t)qorig[t] * 16;
    #pragma unroll
    for (int j = 0; j < 16; j++) {
        int p = si[j];
        float4 cv = cands[p];
        double dxx = qx - (double)cv.x, dyy = qy - (double)cv.y, dzz = qz - (double)cv.z;
        idx_out[ob + j] = aorig[p];
        dst_out[ob + j] = dxx*dxx + dyy*dyy + dzz*dzz;   // f64 exact recompute
    }
}

__global__ __launch_bounds__(64) void ring_both(
    const uint32* __restrict__ bb, const float4* __restrict__ cands,
    const int* __restrict__ offs_a, const int* __restrict__ aorig, int Na,
    const float4* __restrict__ sortedq, const int* __restrict__ qorig, int Np,
    int* __restrict__ idx1, double* __restrict__ dst1,
    int* __restrict__ idx2, double* __restrict__ dst2, int nblk1)
{
    if ((int)blockIdx.x < nblk1)
        ring_search<true >(bb, cands, offs_a, aorig, cands,   aorig, Na, idx1, dst1,
                           blockIdx.x*64 + threadIdx.x);
    else
        ring_search<false>(bb, cands, offs_a, aorig, sortedq, qorig, Np, idx2, dst2,
                           (blockIdx.x - nblk1)*64 + threadIdx.x);
}

// ---------------- fallback brute-force KNN (f64 ranking; ws too small) ----------------
template<bool EXCL>
__device__ __forceinline__ void knn_blockd(
    float4* s_cand, const float* __restrict__ q_xyz, int Nq,
    const float* __restrict__ db, int Nd,
    int* __restrict__ idx_out, double* __restrict__ dist_out, int qblock)
{
    int tid = threadIdx.x;
    int qi = qblock*256 + tid;
    bool active = qi < Nq;
    int q = active ? qi : 0;
    double qx = q_xyz[q*3], qy = q_xyz[q*3+1], qz = q_xyz[q*3+2];
    double tqx = 2.0*qx, tqy = 2.0*qy, tqz = 2.0*qz;
    double sd[16]; int si[16];
    #pragma unroll
    for (int j = 0; j < 16; j++) { sd[j] = SENT*(double)(j+1); si[j] = 0; }
    double cmax = SENT*16.0;
    for (int t0 = 0; t0 < Nd; t0 += 256) {
        __syncthreads();
        int c = t0 + tid;
        if (c < Nd) s_cand[tid] = make_float4(db[c*3], db[c*3+1], db[c*3+2], 0.f);
        __syncthreads();
        int lim = min(256, Nd - t0);
        for (int u = 0; u < lim; u++) {
            float4 cv = s_cand[u];
            double gx = cv.x, gy = cv.y, gz = cv.z;
            double s = gx*(gx - tqx) + gy*(gy - tqy) + gz*(gz - tqz);
            if (EXCL && (t0 + u == q)) continue;
            insert16d(sd, si, cmax, s, t0 + u);
        }
    }
    if (active) {
        #pragma unroll
        for (int kk = 2; kk <= 16; kk <<= 1)
            #pragma unroll
            for (int jj = kk >> 1; jj > 0; jj >>= 1)
                #pragma unroll
                for (int i = 0; i < 16; i++) {
                    int l = i ^ jj;
                    if (l > i) {
                        bool up = ((i & kk) == 0);
                        bool sw = up ? (sd[i] > sd[l]) : (sd[i] < sd[l]);
                        double fa = sw ? sd[l] : sd[i], fb = sw ? sd[i] : sd[l];
                        int    ia = sw ? si[l] : si[i], ib = sw ? si[i] : si[l];
                        sd[i] = fa; sd[l] = fb; si[i] = ia; si[l] = ib;
                    }
                }
        #pragma unroll
        for (int j = 0; j < 16; j++) {
            int ci = si[j];
            double dxx = qx - (double)db[ci*3], dyy = qy - (double)db[ci*3+1], dzz = qz - (double)db[ci*3+2];
            idx_out[(size_t)qi*16 + j] = ci;
            dist_out[(size_t)qi*16 + j] = dxx*dxx + dyy*dyy + dzz*dzz;
        }
    }
}

__global__ __launch_bounds__(256) void knn_both(
    const float* __restrict__ xyz, const float* __restrict__ atom_xyz,
    int Np, int Na,
    int* __restrict__ idx1, double* __restrict__ dst1,
    int* __restrict__ idx2, double* __restrict__ dst2, int nblk1)
{
    __shared__ float4 s_cand[256];
    if ((int)blockIdx.x < nblk1)
        knn_blockd<true >(s_cand, atom_xyz, Na, atom_xyz, Na, idx1, dst1, blockIdx.x);
    else
        knn_blockd<false>(s_cand, xyz, Np, atom_xyz, Na, idx2, dst2, blockIdx.x - nblk1);
}

// ---------------- atomtypes MLP (f32) ----------------
__global__ __launch_bounds__(256) void tt_kernel(
    const float* __restrict__ at,
    const float* __restrict__ w1, const float* __restrict__ b1,
    const float* __restrict__ w2, const float* __restrict__ b2,
    float* __restrict__ out, int Na)
{
    __shared__ float s_w1[DD*DD], s_w2[DD*DD], s_b1[DD], s_b2[DD];
    int tid = threadIdx.x;
    s_w1[tid & 255] = w1[tid & 255];
    s_w2[tid & 255] = w2[tid & 255];
    if (tid < DD) { s_b1[tid] = b1[tid]; s_b2[tid] = b2[tid]; }
    __syncthreads();
    int n = blockIdx.x*256 + tid;
    if (n >= Na) return;
    float f[DD];
    const float4* fp = reinterpret_cast<const float4*>(at + (size_t)n*DD);
    #pragma unroll
    for (int i = 0; i < 4; i++) { float4 v = fp[i]; f[4*i]=v.x; f[4*i+1]=v.y; f[4*i+2]=v.z; f[4*i+3]=v.w; }
    float h[DD];
    #pragma unroll
    for (int j = 0; j < DD; j++) h[j] = s_b1[j];
    #pragma unroll
    for (int e = 0; e < DD; e++) {
        float fe = f[e];
        #pragma unroll
        for (int j = 0; j < DD; j++) h[j] = fmaf(fe, s_w1[e*DD+j], h[j]);
    }
    #pragma unroll
    for (int j = 0; j < DD; j++) h[j] = leakyf(h[j]);
    float m[DD];
    #pragma unroll
    for (int j = 0; j < DD; j++) m[j] = s_b2[j];
    #pragma unroll
    for (int e = 0; e < DD; e++) {
        float he = h[e];
        #pragma unroll
        for (int j = 0; j < DD; j++) m[j] = fmaf(he, s_w2[e*DD+j], m[j]);
    }
    float4* op = reinterpret_cast<float4*>(out + (size_t)n*DD);
    #pragma unroll
    for (int i = 0; i < 4; i++) op[i] = make_float4(m[4*i], m[4*i+1], m[4*i+2], m[4*i+3]);
}

// ---------------- message-passing layer (f32 MLP/state, f64 k-sum + GN) ----------------
__global__ __launch_bounds__(256) void mp_kernel(
    const float* __restrict__ self_feat,   // null => ones (em layer 0)
    const float* __restrict__ nbr_feat,
    const int*    __restrict__ idx,
    const double* __restrict__ dists,
    const float* __restrict__ w1, const float* __restrict__ b1,
    const float* __restrict__ w2, const float* __restrict__ b2,
    const float* __restrict__ gamma, const float* __restrict__ beta,
    float* __restrict__ out_feat, int N)
{
    __shared__ float s_w1[HH*HP];
    __shared__ float s_w2[HH*DD];
    __shared__ float s_b1[HH];
    __shared__ float s_b2[DD], s_g[DD], s_bt[DD];
    int tid = threadIdx.x;
    for (int i = tid; i < HH*HH; i += 256) s_w1[(i/HH)*HP + (i%HH)] = w1[i];
    for (int i = tid; i < HH*DD; i += 256) s_w2[i] = w2[i];
    if (tid < HH) s_b1[tid] = b1[tid];
    if (tid < DD) { s_b2[tid] = b2[tid]; s_g[tid] = gamma[tid]; s_bt[tid] = beta[tid]; }
    __syncthreads();

    int n = blockIdx.x*16 + (tid >> 4);
    int k = tid & 15;
    bool active = n < N;
    int nn = active ? n : (N-1);

    float f[HH];
    if (self_feat) {
        const float4* sp = reinterpret_cast<const float4*>(self_feat + (size_t)nn*DD);
        #pragma unroll
        for (int i = 0; i < 4; i++) { float4 v = sp[i]; f[4*i]=v.x; f[4*i+1]=v.y; f[4*i+2]=v.z; f[4*i+3]=v.w; }
    } else {
        #pragma unroll
        for (int i = 0; i < DD; i++) f[i] = 1.f;
    }
    int nb = idx[(size_t)nn*16 + k];
    {
        const float4* npp = reinterpret_cast<const float4*>(nbr_feat + (size_t)nb*DD);
        #pragma unroll
        for (int i = 0; i < 4; i++) { float4 v = npp[i]; f[DD+4*i]=v.x; f[DD+4*i+1]=v.y; f[DD+4*i+2]=v.z; f[DD+4*i+3]=v.w; }
    }
    f[2*DD] = (float)dists[(size_t)nn*16 + k];

    float h[HH];
    #pragma unroll
    for (int j = 0; j < HH; j++) h[j] = s_b1[j];
    #pragma unroll
    for (int e = 0; e < HH; e++) {
        float fe = f[e];
        const float* wr = &s_w1[e*HP];
        #pragma unroll
        for (int j = 0; j < HH; j++) h[j] = fmaf(fe, wr[j], h[j]);
    }
    #pragma unroll
    for (int j = 0; j < HH; j++) h[j] = leakyf(h[j]);

    float m[DD];
    #pragma unroll
    for (int j = 0; j < DD; j++) m[j] = s_b2[j];
    #pragma unroll
    for (int e = 0; e < HH; e++) {
        float he = h[e];
        const float* wr = &s_w2[e*DD];
        #pragma unroll
        for (int j = 0; j < DD; j++) m[j] = fmaf(he, wr[j], m[j]);
    }

    // k-sum in f64: 16-lane-group butterfly
    double md[DD];
    #pragma unroll
    for (int j = 0; j < DD; j++) md[j] = (double)m[j];
    #pragma unroll
    for (int s = 1; s < 16; s <<= 1) {
        #pragma unroll
        for (int j = 0; j < DD; j++) md[j] += __shfl_xor(md[j], s, 64);
    }

    // group norm over D=16 in f64
    double mu = 0.0;
    #pragma unroll
    for (int j = 0; j < DD; j++) mu += md[j];
    mu *= (1.0/DD);
    double var = 0.0;
    #pragma unroll
    for (int j = 0; j < DD; j++) { double d = md[j] - mu; var = fma(d, d, var); }
    var *= (1.0/DD);
    double inv = 1.0 / sqrt(var + 1e-5);
    double mk = 0.0;   // static-index select (no runtime reg indexing)
    #pragma unroll
    for (int j = 0; j < DD; j++) mk = (j == k) ? md[j] : mk;
    double g = (mk - mu)*inv*(double)s_g[k] + (double)s_bt[k];
    double act = leakyd(g);
    double base = self_feat ? (double)self_feat[(size_t)nn*DD + k] : 1.0;
    if (active) out_feat[(size_t)n*DD + k] = (float)(base + act);
}

extern "C" void kernel_launch(void* const* d_in, const int* in_sizes, int n_in,
                              void* d_out, int out_size, void* d_ws, size_t ws_size,
                              hipStream_t stream)
{
    const float* xyz       = (const float*)d_in[0];
    const float* atom_xyz  = (const float*)d_in[1];
    const float* atomtypes = (const float*)d_in[2];
    const float* tt_w1 = (const float*)d_in[5];
    const float* tt_b1 = (const float*)d_in[6];
    const float* tt_w2 = (const float*)d_in[7];
    const float* tt_b2 = (const float*)d_in[8];
    const float* aa_w1 = (const float*)d_in[9];
    const float* aa_b1 = (const float*)d_in[10];
    const float* aa_w2 = (const float*)d_in[11];
    const float* aa_b2 = (const float*)d_in[12];
    const float* aa_g  = (const float*)d_in[13];
    const float* aa_bt = (const float*)d_in[14];
    const float* em_w1 = (const float*)d_in[15];
    const float* em_b1 = (const float*)d_in[16];
    const float* em_w2 = (const float*)d_in[17];
    const float* em_b2 = (const float*)d_in[18];
    const float* em_g  = (const float*)d_in[19];
    const float* em_bt = (const float*)d_in[20];

    int Np = in_sizes[0] / 3;
    int Na = in_sizes[1] / 3;

    char* w = (char*)d_ws;
    size_t off = 0;
    auto alloc = [&](size_t bytes) -> void* {
        void* p = w + off; off += (bytes + 15) & ~(size_t)15; return p;
    };
    uint32*  bb      = (uint32*)alloc(24);
    int*     hist_a  = (int*)alloc((size_t)G3*4);
    int*     cur_a   = (int*)alloc((size_t)G3*4);
    int*     hist_q  = (int*)alloc((size_t)G3*4);
    int*     cur_q   = (int*)alloc((size_t)G3*4);
    int*     offs_a  = (int*)alloc((size_t)(G3+1)*4);
    int*     offs_q  = (int*)alloc((size_t)(G3+1)*4);
    float4*  cand4s  = (float4*)alloc((size_t)Na*16);
    int*     aorig   = (int*)alloc((size_t)Na*4);
    float4*  sortedq = (float4*)alloc((size_t)Np*16);
    int*     qorig   = (int*)alloc((size_t)Np*4);
    float*   bufA    = (float*)alloc((size_t)Na*DD*4);
    float*   bufB    = (float*)alloc((size_t)Na*DD*4);
    int*     idx1    = (int*)alloc((size_t)Na*16*4);
    double*  dst1    = (double*)alloc((size_t)Na*16*8);
    int*     idx2    = (int*)alloc((size_t)Np*16*4);
    double*  dst2    = (double*)alloc((size_t)Np*16*8);
    size_t need = off;
    float* pe = (float*)d_out;

    if (ws_size >= need) {
        hipMemsetAsync(bb, 0xFF, 12, stream);                    // min slots
        hipMemsetAsync((char*)bb + 12, 0, 12, stream);           // max slots
        hipMemsetAsync(hist_a, 0, (size_t)4*G3*4, stream);       // hist_a,cur_a,hist_q,cur_q
        bbox_kernel<<<dim3(40), 256, 0, stream>>>(atom_xyz, Na, bb);
        int gb = (Na + Np + 255) / 256;
        hist_kernel<<<dim3(gb), 256, 0, stream>>>(atom_xyz, Na, xyz, Np, bb, hist_a, hist_q);
        scan_kernel<<<dim3(2), 1024, 0, stream>>>(hist_a, offs_a, hist_q, offs_q, G3);
        scatter_kernel<<<dim3(gb), 256, 0, stream>>>(atom_xyz, Na, xyz, Np, bb,
            offs_a, cur_a, offs_q, cur_q, cand4s, aorig, sortedq, qorig);
        int nblk1 = (Na + 63) / 64, nblk2 = (Np + 63) / 64;
        ring_both<<<dim3(nblk1 + nblk2), 64, 0, stream>>>(
            bb, cand4s, offs_a, aorig, Na, sortedq, qorig, Np,
            idx1, dst1, idx2, dst2, nblk1);
    } else {
        // fallback: brute-force f64 path with compact layout
        char* v = (char*)d_ws; size_t o2 = 0;
        auto alloc2 = [&](size_t bytes) -> void* {
            void* p = v + o2; o2 += (bytes + 15) & ~(size_t)15; return p;
        };
        bufA = (float*)alloc2((size_t)Na*DD*4);
        bufB = (float*)alloc2((size_t)Na*DD*4);
        idx1 = (int*)alloc2((size_t)Na*16*4);
        dst1 = (double*)alloc2((size_t)Na*16*8);
        idx2 = (int*)alloc2((size_t)Np*16*4);
        dst2 = (double*)alloc2((size_t)Np*16*8);
        int qb1 = (Na + 255)/256, qb2 = (Np + 255)/256;
        knn_both<<<dim3(qb1 + qb2), 256, 0, stream>>>(
            xyz, atom_xyz, Np, Na, idx1, dst1, idx2, dst2, qb1);
    }

    tt_kernel<<<dim3((Na + 255)/256), 256, 0, stream>>>(
        atomtypes, tt_w1, tt_b1, tt_w2, tt_b2, bufA, Na);

    int ga = (Na + 15)/16, ge = (Np + 15)/16;
    // aa layers: ping-pong A->B->A->B
    mp_kernel<<<ga, 256, 0, stream>>>(bufA, bufA, idx1, dst1,
        aa_w1, aa_b1, aa_w2, aa_b2, aa_g, aa_bt, bufB, Na);
    mp_kernel<<<ga, 256, 0, stream>>>(bufB, bufB, idx1, dst1,
        aa_w1 + HH*HH, aa_b1 + HH, aa_w2 + HH*DD, aa_b2 + DD, aa_g + DD, aa_bt + DD, bufA, Na);
    mp_kernel<<<ga, 256, 0, stream>>>(bufA, bufA, idx1, dst1,
        aa_w1 + 2*HH*HH, aa_b1 + 2*HH, aa_w2 + 2*HH*DD, aa_b2 + 2*DD, aa_g + 2*DD, aa_bt + 2*DD, bufB, Na);
    // em layers: atom features fixed (bufB); pe self-only reads -> in-place in d_out
    mp_kernel<<<ge, 256, 0, stream>>>(nullptr, bufB, idx2, dst2,
        em_w1, em_b1, em_w2, em_b2, em_g, em_bt, pe, Np);
    mp_kernel<<<ge, 256, 0, stream>>>(pe, bufB, idx2, dst2,
        em_w1 + HH*HH, em_b1 + HH, em_w2 + HH*DD, em_b2 + DD, em_g + DD, em_bt + DD, pe, Np);
    mp_kernel<<<ge, 256, 0, stream>>>(pe, bufB, idx2, dst2,
        em_w1 + 2*HH*HH, em_b1 + 2*HH, em_w2 + 2*HH*DD, em_b2 + 2*DD, em_g + 2*DD, em_bt + 2*DD, pe, Np);
}